// Round 3
// baseline (90.960 us; speedup 1.0000x reference)
//
#include <hip/hip_runtime.h>
#include <math.h>

#define NQ    13
#define DIM   8192
#define BLOCK 512
#define NGATE 26

// ---- XOR-swizzled LDS addressing (no padding; 64KB state) ----
// bits[3:2] ^= bits[5:4]^bits[7:6];  bit[4] ^= bit[10]^bit[11]
// Bijective; makes pass A/B/C access patterns exactly 2 lanes/bank (free).
__device__ __forceinline__ int SWZ(int i) {
    return i ^ (((((i >> 4) ^ (i >> 6)) & 3)) << 2)
             ^ ((((i >> 10) ^ (i >> 11)) & 1) << 4);
}

// ---- CNOT-chain permutation (GF(2)-linear), compile-time ----
struct PCols { int c[NQ]; };
constexpr PCols make_cols(int r) {
    PCols P{};
    for (int b = 0; b < NQ; ++b) {
        int cc = 1 << b;
        for (int cq = 0; cq < NQ; ++cq) {
            const int cb = 12 - cq;
            const int tb = 12 - ((cq + r) % NQ);
            cc ^= ((cc >> cb) & 1) << tb;
        }
        P.c[b] = cc;
    }
    return P;
}
constexpr PCols C1 = make_cols(1);   // layer 0 CNOTs (r=1)
constexpr int make_rm6() {           // row 6 of layer-1 (r=2) permutation matrix
    int m = 0;
    for (int b = 0; b < NQ; ++b) m |= ((make_cols(2).c[b] >> 6) & 1) << b;
    return m;
}
constexpr int RM6 = make_rm6();

// scatter combos for pass-C reg bits: j0=i0, j1=i1, j2=i2, j3=i12
struct Combos { int k[16]; };
constexpr Combos make_combos() {
    Combos K{};
    for (int j = 0; j < 16; ++j)
        K.k[j] = ((j & 1) ? C1.c[0] : 0) ^ ((j & 2) ? C1.c[1] : 0)
               ^ ((j & 4) ? C1.c[2] : 0) ^ ((j & 8) ? C1.c[12] : 0);
    return K;
}
constexpr Combos KC = make_combos();

// ---- gate matrix: u00=(a.x,a.y) u01=(a.z,a.w) u10=(b.x,b.y) u11=(b.z,b.w) ----
struct G8 { float4 a, b; };

// Rot gate on 16-amp register subcube, pair bit = local position P
template<int P>
__device__ __forceinline__ void rot16(float* vr, float* vi, const G8 g) {
    #pragma unroll
    for (int m = 0; m < 8; ++m) {
        const int j0 = ((m >> P) << (P + 1)) | (m & ((1 << P) - 1));
        const int j1 = j0 | (1 << P);
        const float a0r = vr[j0], a0i = vi[j0];
        const float a1r = vr[j1], a1i = vi[j1];
        vr[j0] = g.a.x * a0r - g.a.y * a0i + g.a.z * a1r - g.a.w * a1i;
        vi[j0] = g.a.x * a0i + g.a.y * a0r + g.a.z * a1i + g.a.w * a1r;
        vr[j1] = g.b.x * a0r - g.b.y * a0i + g.b.z * a1r - g.b.w * a1i;
        vi[j1] = g.b.x * a0i + g.b.y * a0r + g.b.z * a1i + g.b.w * a1r;
    }
}

// DPP quad-perm lane exchange: CTRL=0xB1 -> lane^1, CTRL=0x4E -> lane^2
template<int CTRL>
__device__ __forceinline__ float dppx(float v) {
    return __int_as_float(
        __builtin_amdgcn_update_dpp(0, __float_as_int(v), CTRL, 0xf, 0xf, true));
}

// Rot gate where the pair bit lives in a lane bit (quad-local), via DPP.
// hi = this lane's value of the gate bit. new = A*own + B*partner,
// (A,B) = hi ? (u11,u10) : (u00,u01).
template<int CTRL>
__device__ __forceinline__ void rotlane16(float* vr, float* vi, const G8 g, const bool hi) {
    const float Ar = hi ? g.b.z : g.a.x;
    const float Ai = hi ? g.b.w : g.a.y;
    const float Br = hi ? g.b.x : g.a.z;
    const float Bi = hi ? g.b.y : g.a.w;
    #pragma unroll
    for (int j = 0; j < 16; ++j) {
        const float pr = dppx<CTRL>(vr[j]);
        const float pi = dppx<CTRL>(vi[j]);
        const float orr = vr[j], oii = vi[j];
        vr[j] = Ar * orr - Ai * oii + Br * pr - Bi * pi;
        vi[j] = Ar * oii + Ai * orr + Br * pi + Bi * pr;
    }
}

// ---- pass A: i = t<<4 | j ; reg bits 0-3 (q12..q9), dpp bits 4,5 (q8,q7) ----
__device__ __forceinline__ void passA(float* re, float* im, const G8* __restrict__ gw,
                                      const int l, const int t) {
    float vr[16], vi[16];
    const int base = t << 4;
    #pragma unroll
    for (int g = 0; g < 4; ++g) {
        const int a = SWZ(base + 4 * g);
        *(float4*)&vr[4 * g] = *(const float4*)&re[a];
        *(float4*)&vi[4 * g] = *(const float4*)&im[a];
    }
    rot16<0>(vr, vi, gw[l * 13 + 12]);
    rot16<1>(vr, vi, gw[l * 13 + 11]);
    rot16<2>(vr, vi, gw[l * 13 + 10]);
    rot16<3>(vr, vi, gw[l * 13 +  9]);
    rotlane16<0xB1>(vr, vi, gw[l * 13 + 8], (t & 1) != 0);
    rotlane16<0x4E>(vr, vi, gw[l * 13 + 7], (t & 2) != 0);
    #pragma unroll
    for (int g = 0; g < 4; ++g) {
        const int a = SWZ(base + 4 * g);
        *(float4*)&re[a] = *(const float4*)&vr[4 * g];
        *(float4*)&im[a] = *(const float4*)&vi[4 * g];
    }
}

// ---- pass B: t = i12<<8 | i[5:0]<<2 | i[11:10]; reg bits 6-9 (q6..q3),
//              dpp bits 10,11 (q2,q1) ----
__device__ __forceinline__ void passB(float* re, float* im, const G8* __restrict__ gw,
                                      const int l, const int t) {
    float vr[16], vi[16];
    const int base = ((t >> 8) << 12) | ((t & 3) << 10) | ((t >> 2) & 63);
    const int sb = SWZ(base);   // j-slot bits (6-9) are zero in base
    #pragma unroll
    for (int j = 0; j < 16; ++j) {
        const int a = sb ^ (j << 6) ^ ((j & 3) << 2);
        vr[j] = re[a]; vi[j] = im[a];
    }
    rot16<0>(vr, vi, gw[l * 13 + 6]);
    rot16<1>(vr, vi, gw[l * 13 + 5]);
    rot16<2>(vr, vi, gw[l * 13 + 4]);
    rot16<3>(vr, vi, gw[l * 13 + 3]);
    rotlane16<0xB1>(vr, vi, gw[l * 13 + 2], (t & 1) != 0);
    rotlane16<0x4E>(vr, vi, gw[l * 13 + 1], (t & 2) != 0);
    #pragma unroll
    for (int j = 0; j < 16; ++j) {
        const int a = sb ^ (j << 6) ^ ((j & 3) << 2);
        re[a] = vr[j]; im[a] = vi[j];
    }
}

// ---- pass C loads: t = i[11:3]; reg j = i12<<3 | i[2:0]  (gate bit 12 = q0) ----
__device__ __forceinline__ void passC_load(const float* re, const float* im,
                                           float* vr, float* vi, const int t) {
    #pragma unroll
    for (int h = 0; h < 2; ++h)
        #pragma unroll
        for (int k = 0; k < 2; ++k) {
            const int a = SWZ((h << 12) | (t << 3) | (k << 2));
            *(float4*)&vr[h * 8 + 4 * k] = *(const float4*)&re[a];
            *(float4*)&vi[h * 8 + 4 * k] = *(const float4*)&im[a];
        }
}

__global__ void prep_gates(const float* __restrict__ w, G8* __restrict__ gw) {
    const int t = threadIdx.x;
    if (t < NGATE) {
        const float phi = w[t * 3 + 0], theta = w[t * 3 + 1], omega = w[t * 3 + 2];
        float c, s;  sincosf(0.5f * theta, &s, &c);
        float sps, cps, sds, cds;
        sincosf(0.5f * (phi + omega), &sps, &cps);
        sincosf(0.5f * (phi - omega), &sds, &cds);
        G8 g;
        g.a = make_float4(cps * c, -sps * c, -cds * s, -sds * s);  // u00, u01
        g.b = make_float4(cds * s, -sds * s,  cps * c,  sps * c);  // u10, u11
        gw[t] = g;
    }
}

__global__ __launch_bounds__(BLOCK, 4) void qsim_kernel(
    const float* __restrict__ x,
    const G8* __restrict__ gw,
    float* __restrict__ out)
{
    __shared__ float re[DIM];
    __shared__ float im[DIM];
    __shared__ float red[BLOCK / 64];

    const int b = blockIdx.x;
    const int t = threadIdx.x;

    // ---- P0: coalesced global -> LDS (swizzled), sum of squares ----
    const float4* x4 = (const float4*)(x + (size_t)b * DIM);
    float ss = 0.f;
    #pragma unroll
    for (int k = 0; k < 4; ++k) {
        const int m = t + BLOCK * k;
        const int a = SWZ(4 * m);
        const float4 v = x4[m];
        *(float4*)&re[a] = v;
        *(float4*)&im[a] = make_float4(0.f, 0.f, 0.f, 0.f);
        ss += v.x * v.x + v.y * v.y + v.z * v.z + v.w * v.w;
    }
    #pragma unroll
    for (int off = 32; off > 0; off >>= 1) ss += __shfl_down(ss, off, 64);
    if ((t & 63) == 0) red[t >> 6] = ss;
    __syncthreads();
    float total = 0.f;
    #pragma unroll
    for (int i = 0; i < BLOCK / 64; ++i) total += red[i];  // ||x||^2, invariant

    float vr[16], vi[16];

    // ================= layer 0 =================
    passA(re, im, gw, 0, t);
    __syncthreads();
    passB(re, im, gw, 0, t);
    __syncthreads();
    passC_load(re, im, vr, vi, t);
    rot16<3>(vr, vi, gw[0 * 13 + 0]);          // bit 12 (qubit 0)
    __syncthreads();                            // all reads of old state done
    {   // all 13 layer-0 CNOTs as one linear scatter
        int tpart = 0;
        #pragma unroll
        for (int bb = 0; bb < 9; ++bb)
            if ((t >> bb) & 1) tpart ^= C1.c[3 + bb];
        #pragma unroll
        for (int j = 0; j < 16; ++j) {
            const int a = SWZ(tpart ^ KC.k[j]);
            re[a] = vr[j]; im[a] = vi[j];
        }
    }
    __syncthreads();

    // ================= layer 1 =================
    passA(re, im, gw, 1, t);
    __syncthreads();
    passB(re, im, gw, 1, t);
    __syncthreads();
    passC_load(re, im, vr, vi, t);
    rot16<3>(vr, vi, gw[1 * 13 + 0]);          // bit 12 (qubit 0)

    // layer-1 CNOTs + PauliZ(q6) folded: sign = popc(i & RM6) & 1
    float acc = 0.f;
    #pragma unroll
    for (int j = 0; j < 16; ++j) {
        const int i = ((j >> 3) << 12) | (t << 3) | (j & 7);
        const float p = vr[j] * vr[j] + vi[j] * vi[j];
        acc += (__popc(i & RM6) & 1) ? -p : p;
    }
    #pragma unroll
    for (int off = 32; off > 0; off >>= 1) acc += __shfl_down(acc, off, 64);
    __syncthreads();                   // red[] safe to reuse
    if ((t & 63) == 0) red[t >> 6] = acc;
    __syncthreads();
    if (t == 0) {
        float tot = 0.f;
        #pragma unroll
        for (int i = 0; i < BLOCK / 64; ++i) tot += red[i];
        out[b] = tot / total;
    }
}

extern "C" void kernel_launch(void* const* d_in, const int* in_sizes, int n_in,
                              void* d_out, int out_size, void* d_ws, size_t ws_size,
                              hipStream_t stream) {
    const float* x = (const float*)d_in[0];   // (512, 8192) fp32
    const float* w = (const float*)d_in[1];   // (2, 13, 3) fp32
    float* out = (float*)d_out;               // (512,) fp32
    G8* gw = (G8*)d_ws;                       // 26 * 32 B = 832 B scratch
    const int B = in_sizes[0] / DIM;
    prep_gates<<<1, 64, 0, stream>>>(w, gw);
    qsim_kernel<<<B, BLOCK, 0, stream>>>(x, (const G8*)gw, out);
}

// Round 4
// 85.398 us; speedup vs baseline: 1.0651x; 1.0651x over previous
//
#include <hip/hip_runtime.h>
#include <math.h>

#define NQ    13
#define DIM   8192
#define BLOCK 512
#define NGATE 26

// Bank-quad spreading swizzle: XOR addr[4:2] with addr[9:7]. Preserves
// addr[1:0] => b128 groups stay intact. Applied at every LDS access.
__device__ __forceinline__ int SW(int a) { return a ^ (((a >> 7) & 7) << 2); }

// ---- CNOT-chain permutation (GF(2)-linear), compile-time ----
struct PCols { int c[NQ]; };
constexpr PCols make_cols(int r) {
    PCols P{};
    for (int b = 0; b < NQ; ++b) {
        int cc = 1 << b;
        for (int cq = 0; cq < NQ; ++cq) {
            const int cb = 12 - cq;
            const int tb = 12 - ((cq + r) % NQ);
            cc ^= ((cc >> cb) & 1) << tb;
        }
        P.c[b] = cc;
    }
    return P;
}
constexpr PCols C1 = make_cols(1);   // layer 0 CNOTs (r=1)
constexpr int make_rm6() {           // row 6 of layer-1 (r=2) permutation matrix
    int m = 0;
    for (int b = 0; b < NQ; ++b) m |= ((make_cols(2).c[b] >> 6) & 1) << b;
    return m;
}
constexpr int RM6 = make_rm6();

// scatter combos for pass-3 reg bits: j0->i0, j1->i1, j2->i10, j3->i11
struct Combos { int k[16]; };
constexpr Combos make_combos() {
    Combos K{};
    for (int j = 0; j < 16; ++j)
        K.k[j] = ((j & 1) ? C1.c[0] : 0) ^ ((j & 2) ? C1.c[1] : 0)
               ^ ((j & 4) ? C1.c[10] : 0) ^ ((j & 8) ? C1.c[11] : 0);
    return K;
}
constexpr Combos KC = make_combos();

// per-j PauliZ sign parity for the final reduce (j bits -> i bits {0,1,10,11})
constexpr int make_sjw() {
    int wv = 0;
    for (int j = 0; j < 16; ++j) {
        const int jm = (j & 3) | (((j >> 2) & 3) << 10);
        wv |= (__builtin_popcount(jm & RM6) & 1) << j;
    }
    return wv;
}
constexpr int SJW = make_sjw();

// ---- float2 complex helpers (paired ops -> candidate v_pk_fma_f32) ----
__device__ __forceinline__ float2 f2mul(float s, float2 a) {
    return make_float2(s * a.x, s * a.y);
}
__device__ __forceinline__ float2 f2fma(float s, float2 a, float2 b) {
    return make_float2(fmaf(s, a.x, b.x), fmaf(s, a.y, b.y));
}
__device__ __forceinline__ float2 fswap(float2 a) { return make_float2(-a.y, a.x); }

// gate storage: g[8] = {u00r,u00i, u01r,u01i, u10r,u10i, u11r,u11i}
template<int P>
__device__ __forceinline__ void rotp(float2* c, const float* __restrict__ g) {
    const float ur00 = g[0], ui00 = g[1], ur01 = g[2], ui01 = g[3];
    const float ur10 = g[4], ui10 = g[5], ur11 = g[6], ui11 = g[7];
    #pragma unroll
    for (int m = 0; m < 8; ++m) {
        const int j0 = ((m >> P) << (P + 1)) | (m & ((1 << P) - 1));
        const int j1 = j0 | (1 << P);
        const float2 a0 = c[j0], a1 = c[j1];
        const float2 s0 = fswap(a0), s1 = fswap(a1);
        c[j0] = f2fma(ui01, s1, f2fma(ur01, a1, f2fma(ui00, s0, f2mul(ur00, a0))));
        c[j1] = f2fma(ui11, s1, f2fma(ur11, a1, f2fma(ui10, s0, f2mul(ur10, a0))));
    }
}

// DPP quad-perm lane exchange: 0xB1 -> lane^1, 0x4E -> lane^2
template<int CTRL>
__device__ __forceinline__ float dppx(float v) {
    return __int_as_float(
        __builtin_amdgcn_update_dpp(0, __float_as_int(v), CTRL, 0xf, 0xf, true));
}
template<int CTRL>
__device__ __forceinline__ void rotlane(float2* c, const float* __restrict__ g, const bool hi) {
    const float Ar = hi ? g[6] : g[0];
    const float Ai = hi ? g[7] : g[1];
    const float Br = hi ? g[4] : g[2];
    const float Bi = hi ? g[5] : g[3];
    #pragma unroll
    for (int j = 0; j < 16; ++j) {
        const float2 p  = make_float2(dppx<CTRL>(c[j].x), dppx<CTRL>(c[j].y));
        const float2 so = fswap(c[j]), sp = fswap(p);
        c[j] = f2fma(Bi, sp, f2fma(Br, p, f2fma(Ai, so, f2mul(Ar, c[j]))));
    }
}

__device__ __forceinline__ void loadgrp(const float* re, const float* im, int a, float2* c) {
    const float4 r = *(const float4*)&re[a];
    const float4 i = *(const float4*)&im[a];
    c[0] = make_float2(r.x, i.x); c[1] = make_float2(r.y, i.y);
    c[2] = make_float2(r.z, i.z); c[3] = make_float2(r.w, i.w);
}
__device__ __forceinline__ void storegrp(float* re, float* im, int a, const float2* c) {
    *(float4*)&re[a] = make_float4(c[0].x, c[1].x, c[2].x, c[3].x);
    *(float4*)&im[a] = make_float4(c[0].y, c[1].y, c[2].y, c[3].y);
}

__global__ __launch_bounds__(BLOCK, 4) void qsim_kernel(
    const float* __restrict__ x,
    const float* __restrict__ w,
    float* __restrict__ out)
{
    __shared__ __align__(16) float re[DIM];
    __shared__ __align__(16) float im[DIM];
    __shared__ float gm[NGATE * 8];
    __shared__ float red[BLOCK / 64];

    const int b = blockIdx.x;
    const int t = threadIdx.x;

    // ---- gate matrices, 26 threads, once per block ----
    if (t < NGATE) {
        const float phi = w[t * 3 + 0], theta = w[t * 3 + 1], omega = w[t * 3 + 2];
        float co, si;  sincosf(0.5f * theta, &si, &co);
        float sps, cps, sds, cds;
        sincosf(0.5f * (phi + omega), &sps, &cps);
        sincosf(0.5f * (phi - omega), &sds, &cds);
        float* g = &gm[t * 8];
        g[0] =  cps * co;  g[1] = -sps * co;   // u00
        g[2] = -cds * si;  g[3] = -sds * si;   // u01
        g[4] =  cds * si;  g[5] = -sds * si;   // u10
        g[6] =  cps * co;  g[7] =  sps * co;   // u11
    }

    // ---- P0: coalesced global -> LDS (swizzled), sum of squares ----
    const float4* x4 = (const float4*)(x + (size_t)b * DIM);
    float ss = 0.f;
    #pragma unroll
    for (int k = 0; k < 4; ++k) {
        const int m = t + BLOCK * k;
        const int a = SW(4 * m);
        const float4 v = x4[m];
        *(float4*)&re[a] = v;
        *(float4*)&im[a] = make_float4(0.f, 0.f, 0.f, 0.f);
        ss += v.x * v.x + v.y * v.y + v.z * v.z + v.w * v.w;
    }
    #pragma unroll
    for (int off = 32; off > 0; off >>= 1) ss += __shfl_down(ss, off, 64);
    if ((t & 63) == 0) red[t >> 6] = ss;
    __syncthreads();
    float total = 0.f;
    #pragma unroll
    for (int i = 0; i < BLOCK / 64; ++i) total += red[i];  // ||x||^2, invariant

    float2 c[16];

    // Per-pass (t,j)->i mappings (all in-place, all b128):
    //  P1: i = t<<4 | j            reg i[3:0] (q12..q9), dpp i[5:4]=t[1:0] (q8,q7)
    //  P2: i[1:0]=j[1:0], i[7:6]=j[3:2], i[5:2]=t[5:2], i[9:8]=t[1:0], i[12:10]=t[8:6]
    //      reg gates i6,i7 (q6,q5), dpp i8,i9 (q4,q3)
    //  P3: i[1:0]=j[1:0], i[11:10]=j[3:2], i[9:2]=t[8:1], i12=t[0]
    //      reg gates i10,i11 (q2,q1), dpp i12 (q0)
    const int base2 = (((t >> 2) & 15) << 2) | ((t & 3) << 8) | (((t >> 6) & 7) << 10);
    const int base3 = (((t >> 1) & 255) << 2) | ((t & 1) << 12);

    #pragma unroll
    for (int l = 0; l < 2; ++l) {
        const float* G = gm + l * 13 * 8;

        // ---- pass 1: 6 gates (q12..q7) ----
        #pragma unroll
        for (int g = 0; g < 4; ++g) loadgrp(re, im, SW((t << 4) | (g << 2)), &c[4 * g]);
        rotp<0>(c, G + 12 * 8);
        rotp<1>(c, G + 11 * 8);
        rotp<2>(c, G + 10 * 8);
        rotp<3>(c, G +  9 * 8);
        rotlane<0xB1>(c, G + 8 * 8, (t & 1) != 0);
        rotlane<0x4E>(c, G + 7 * 8, (t & 2) != 0);
        #pragma unroll
        for (int g = 0; g < 4; ++g) storegrp(re, im, SW((t << 4) | (g << 2)), &c[4 * g]);
        __syncthreads();

        // ---- pass 2: 4 gates (q6..q3) ----
        #pragma unroll
        for (int h = 0; h < 4; ++h) loadgrp(re, im, SW(base2 | (h << 6)), &c[4 * h]);
        rotp<2>(c, G + 6 * 8);
        rotp<3>(c, G + 5 * 8);
        rotlane<0xB1>(c, G + 4 * 8, (t & 1) != 0);
        rotlane<0x4E>(c, G + 3 * 8, (t & 2) != 0);
        #pragma unroll
        for (int h = 0; h < 4; ++h) storegrp(re, im, SW(base2 | (h << 6)), &c[4 * h]);
        __syncthreads();

        // ---- pass 3: 3 gates (q2,q1,q0) ----
        #pragma unroll
        for (int h = 0; h < 4; ++h) loadgrp(re, im, SW(base3 | (h << 10)), &c[4 * h]);
        __syncthreads();               // all reads of old state complete
        rotp<2>(c, G + 2 * 8);
        rotp<3>(c, G + 1 * 8);
        rotlane<0xB1>(c, G + 0 * 8, (t & 1) != 0);

        if (l == 0) {
            // all 13 layer-0 CNOTs as one GF(2)-linear scatter back to identity layout
            int mb = 0;
            if (t & 1) mb ^= C1.c[12];
            #pragma unroll
            for (int bb = 0; bb < 8; ++bb)
                if ((t >> (bb + 1)) & 1) mb ^= C1.c[2 + bb];
            #pragma unroll
            for (int j = 0; j < 16; ++j) {
                const int a = SW(mb ^ KC.k[j]);
                re[a] = c[j].x; im[a] = c[j].y;
            }
            __syncthreads();
        }
    }

    // ---- layer-1 CNOTs + PauliZ(q6) folded: sign = popc(i & RM6) & 1 ----
    const int sbase = __popc(base3 & RM6) & 1;   // base3 == thread's fixed i-bits
    float acc = 0.f;
    #pragma unroll
    for (int j = 0; j < 16; ++j) {
        const float p = c[j].x * c[j].x + c[j].y * c[j].y;
        acc += (sbase ^ ((SJW >> j) & 1)) ? -p : p;
    }
    #pragma unroll
    for (int off = 32; off > 0; off >>= 1) acc += __shfl_down(acc, off, 64);
    if ((t & 63) == 0) red[t >> 6] = acc;
    __syncthreads();
    if (t == 0) {
        float tot = 0.f;
        #pragma unroll
        for (int i = 0; i < BLOCK / 64; ++i) tot += red[i];
        out[b] = tot / total;
    }
}

extern "C" void kernel_launch(void* const* d_in, const int* in_sizes, int n_in,
                              void* d_out, int out_size, void* d_ws, size_t ws_size,
                              hipStream_t stream) {
    const float* x = (const float*)d_in[0];   // (512, 8192) fp32
    const float* w = (const float*)d_in[1];   // (2, 13, 3) fp32
    float* out = (float*)d_out;               // (512,) fp32
    const int B = in_sizes[0] / DIM;
    qsim_kernel<<<B, BLOCK, 0, stream>>>(x, w, out);
}